// Round 4
// baseline (1206.056 us; speedup 1.0000x reference)
//
#include <hip/hip_runtime.h>
#include <math.h>

// PointcloudToVoxels: B=4 batches, C=32 channels, N=200k points,
// 64x64x64 grid, V = 262144 voxels.
// Output layout: [B,C,V] voxeldata (float32) then [B,1,V] occupancy (float32).

#define GW 64
#define GL 64
#define GH 64
#define GV (GW * GL * GH)   // 262144 = 2^18
#define NB 4
#define MIN_PTS 10

// Monotonic order-preserving float32 <-> uint32 encoding.
// All finite floats encode to > 0, so a 0-initialized buffer acts as -inf
// under unsigned atomicMax.
__device__ __forceinline__ unsigned enc_f32(float f) {
    unsigned u = __float_as_uint(f);
    return (u & 0x80000000u) ? ~u : (u | 0x80000000u);
}
__device__ __forceinline__ float dec_f32(unsigned u) {
    return (u & 0x80000000u) ? __uint_as_float(u & 0x7FFFFFFFu)
                             : __uint_as_float(~u);
}

// Binning that bit-matches XLA's compilation of floor(x/0.05 + 0.5):
// XLA folds x/0.05 -> x * 20.0f (fl32(1/0.05) == 20.0f exactly);
// __fmul_rn/__fadd_rn forbid FMA contraction. [R3: absmax 0.0 with this.]
__device__ __forceinline__ int bin_coord(float x) {
    float m = __fmul_rn(x, 20.0f);
    float r = __fadd_rn(m, 0.5f);
    return (int)floorf(r);
}

// ---------------------------------------------------------------------------
// Generic zero-init of a uint4 span.
__global__ void zero_kernel(uint4* __restrict__ p, int n4) {
    int i = blockIdx.x * blockDim.x + threadIdx.x;
    if (i < n4) p[i] = make_uint4(0u, 0u, 0u, 0u);
}

// ---------------------------------------------------------------------------
// FAST PATH (C==32, ws >= 132 MB): max-accumulator in d_ws with [B,V,C]
// layout so one point's 32 channel atomics hit ONE aligned 128B region
// (R3 evidence: [B,C,V] layout spread them 1MB apart -> 790MB WRITE_SIZE of
// thrashed 32B sectors, 955us. Here: line reused 32x back-to-back).
__global__ void scatter_vc_kernel(const float* __restrict__ coords,
                                  const float* __restrict__ attrs,
                                  unsigned* __restrict__ vbits,
                                  int* __restrict__ counts,
                                  int N) {
    int n = blockIdx.x * blockDim.x + threadIdx.x;
    int b = blockIdx.y;
    if (n >= N) return;

    const float* pc = coords + (size_t)b * 3 * N;
    int ix = bin_coord(pc[n]);
    int iy = bin_coord(pc[n + N]);
    int iz = bin_coord(pc[n + 2 * N]);
    if ((unsigned)ix >= (unsigned)GW || (unsigned)iy >= (unsigned)GL ||
        (unsigned)iz >= (unsigned)GH)
        return;

    int v = (ix << 12) | (iy << 6) | iz;
    atomicAdd(&counts[b * GV + v], 1);

    const float* pa = attrs + (size_t)b * 32 * N + n;
    unsigned* pb = vbits + (((size_t)b * GV + v) << 5);   // 128B-aligned
#pragma unroll
    for (int c = 0; c < 32; ++c) {
        atomicMax(&pb[c], enc_f32(pa[(size_t)c * N]));
    }
}

// Transpose [B,V,C] bits -> [B,C,V] voxeldata (masked by count>0) and write
// occupancy, all coalesced. Tile: 64 voxels x 32 channels, LDS pad +1
// (2-way bank aliasing only -- free on gfx950).
__global__ void transpose_finalize_kernel(const unsigned* __restrict__ vbits,
                                          const int* __restrict__ counts,
                                          float* __restrict__ vdata,
                                          float* __restrict__ occ) {
    __shared__ unsigned tile[64][33];
    __shared__ int cnt[64];
    int b = blockIdx.y;
    int base = blockIdx.x << 6;                 // tile of 64 voxels
    int t = threadIdx.x;                        // 0..255

    // Load 2048 contiguous dwords; each thread 8 (stays within one voxel row).
    const unsigned* src = vbits + (((size_t)b * GV + base) << 5);
    int idx = t << 3;
    int v0 = idx >> 5;
    int c0 = idx & 31;
    uint4 u0 = *(const uint4*)&src[idx];
    uint4 u1 = *(const uint4*)&src[idx + 4];
    tile[v0][c0 + 0] = u0.x; tile[v0][c0 + 1] = u0.y;
    tile[v0][c0 + 2] = u0.z; tile[v0][c0 + 3] = u0.w;
    tile[v0][c0 + 4] = u1.x; tile[v0][c0 + 5] = u1.y;
    tile[v0][c0 + 6] = u1.z; tile[v0][c0 + 7] = u1.w;
    if (t < 64) cnt[t] = counts[b * GV + base + t];
    __syncthreads();

    float* dst = vdata + (size_t)b * 32 * GV + base;
    int v = t & 63;
    int cb = t >> 6;                            // 0..3
    bool nz = cnt[v] > 0;
#pragma unroll
    for (int k = 0; k < 8; ++k) {
        int c = (k << 2) + cb;
        float val = nz ? dec_f32(tile[v][c]) : 0.0f;
        dst[(size_t)c * GV + v] = val;          // 64 consecutive dwords/wave-half
    }
    if (t < 64) occ[(size_t)b * GV + base + t] = cnt[t] >= MIN_PTS ? 1.0f : 0.0f;
}

// ---------------------------------------------------------------------------
// FALLBACK PATH (R3 kernels): bits in d_out [B,C,V], in-place finalize.
__global__ void init_kernel(uint4* __restrict__ data4, uint4* __restrict__ cnt4,
                            int nData4, int nCnt4) {
    int i = blockIdx.x * blockDim.x + threadIdx.x;
    uint4 z = make_uint4(0u, 0u, 0u, 0u);
    if (i < nData4) {
        data4[i] = z;
    } else if (i < nData4 + nCnt4) {
        cnt4[i - nData4] = z;
    }
}

__global__ void scatter_kernel(const float* __restrict__ coords,
                               const float* __restrict__ attrs,
                               unsigned* __restrict__ bits,
                               int* __restrict__ counts,
                               int N, int C) {
    int n = blockIdx.x * blockDim.x + threadIdx.x;
    int b = blockIdx.y;
    if (n >= N) return;

    const float* pc = coords + (size_t)b * 3 * N;
    int ix = bin_coord(pc[n]);
    int iy = bin_coord(pc[n + N]);
    int iz = bin_coord(pc[n + 2 * N]);
    if ((unsigned)ix >= (unsigned)GW || (unsigned)iy >= (unsigned)GL ||
        (unsigned)iz >= (unsigned)GH)
        return;

    int v = (ix << 12) | (iy << 6) | iz;
    atomicAdd(&counts[b * GV + v], 1);

    const float* pa = attrs + (size_t)b * C * N + n;
    unsigned* pb = bits + (size_t)b * C * GV + v;
#pragma unroll 8
    for (int c = 0; c < C; ++c) {
        unsigned e = enc_f32(pa[(size_t)c * N]);
        atomicMax(&pb[(size_t)c * GV], e);
    }
}

__global__ void finalize_kernel(unsigned* __restrict__ data,
                                const int* __restrict__ counts,
                                float* __restrict__ occ,
                                int C) {
    int i = blockIdx.x * blockDim.x + threadIdx.x;
    int nData4 = NB * C * GV / 4;
    int nOcc4 = NB * GV / 4;
    if (i < nData4) {
        int idx = i << 2;
        int v = idx & (GV - 1);
        int b = idx / (C * GV);
        int4 cntv = *(const int4*)&counts[b * GV + v];
        uint4 u = *(const uint4*)&data[idx];
        float4 r;
        r.x = cntv.x > 0 ? dec_f32(u.x) : 0.0f;
        r.y = cntv.y > 0 ? dec_f32(u.y) : 0.0f;
        r.z = cntv.z > 0 ? dec_f32(u.z) : 0.0f;
        r.w = cntv.w > 0 ? dec_f32(u.w) : 0.0f;
        *(float4*)&data[idx] = r;
    } else if (i < nData4 + nOcc4) {
        int j = (i - nData4) << 2;
        int4 cntv = *(const int4*)&counts[j];
        float4 r;
        r.x = cntv.x >= MIN_PTS ? 1.0f : 0.0f;
        r.y = cntv.y >= MIN_PTS ? 1.0f : 0.0f;
        r.z = cntv.z >= MIN_PTS ? 1.0f : 0.0f;
        r.w = cntv.w >= MIN_PTS ? 1.0f : 0.0f;
        *(float4*)&occ[j] = r;
    }
}

// ---------------------------------------------------------------------------
extern "C" void kernel_launch(void* const* d_in, const int* in_sizes, int n_in,
                              void* d_out, int out_size, void* d_ws, size_t ws_size,
                              hipStream_t stream) {
    const float* coords = (const float*)d_in[0];  // [B,3,N]
    const float* attrs  = (const float*)d_in[1];  // [B,C,N]
    int N = in_sizes[0] / (NB * 3);
    int C = in_sizes[1] / (NB * N);

    size_t fastWs = (size_t)NB * GV * 32 * 4 + (size_t)NB * GV * 4;  // 132 MB

    if (C == 32 && ws_size >= fastWs) {
        unsigned* vbits = (unsigned*)d_ws;                      // [B,V,32]
        int* counts = (int*)d_ws + (size_t)NB * GV * 32;        // [B,V]
        float* vdata = (float*)d_out;                           // [B,32,V]
        float* occ = (float*)d_out + (size_t)NB * 32 * GV;      // [B,1,V]

        int n4 = (int)(fastWs / 16);                            // uint4 count
        zero_kernel<<<(n4 + 255) / 256, 256, 0, stream>>>((uint4*)d_ws, n4);

        dim3 sgrid((N + 255) / 256, NB);
        scatter_vc_kernel<<<sgrid, 256, 0, stream>>>(coords, attrs, vbits,
                                                     counts, N);

        dim3 fgrid(GV / 64, NB);
        transpose_finalize_kernel<<<fgrid, 256, 0, stream>>>(vbits, counts,
                                                             vdata, occ);
    } else {
        unsigned* bits = (unsigned*)d_out;                      // [B,C,V]
        float* occ = (float*)d_out + (size_t)NB * C * GV;
        int* counts = (int*)d_ws;

        int nData4 = NB * C * GV / 4;
        int nCnt4  = NB * GV / 4;
        int initTotal = nData4 + nCnt4;
        init_kernel<<<(initTotal + 255) / 256, 256, 0, stream>>>(
            (uint4*)d_out, (uint4*)d_ws, nData4, nCnt4);

        dim3 sgrid((N + 255) / 256, NB);
        scatter_kernel<<<sgrid, 256, 0, stream>>>(coords, attrs, bits, counts,
                                                  N, C);

        finalize_kernel<<<(initTotal + 255) / 256, 256, 0, stream>>>(
            bits, counts, occ, C);
    }
}

// Round 5
// 451.441 us; speedup vs baseline: 2.6716x; 2.6716x over previous
//
#include <hip/hip_runtime.h>
#include <math.h>

// PointcloudToVoxels: B=4 batches, C=32 channels, N=200k points,
// 64x64x64 grid, V = 262144 voxels.
// Output layout: [B,C,V] voxeldata (float32) then [B,1,V] occupancy (float32).
//
// R4 finding: device-scope atomics execute memory-side (per-XCD L2s are not
// coherent), so EVERY atomic is a ~32B fabric RMW regardless of locality:
// WRITE_SIZE == 31B x n_atomics for both [B,C,V] and [B,V,C] accumulator
// layouts, ~26 G atomics/s ceiling -> 1000us for 26.4M atomics.
// Fix: counting sort (1 atomic per POINT, not per point-channel) + segmented
// max with plain loads. 33x fewer atomics.

#define GW 64
#define GL 64
#define GH 64
#define GV (GW * GL * GH)   // 262144 = 2^18
#define NB 4
#define MIN_PTS 10

// Binning that bit-matches XLA's compilation of floor(x/0.05 + 0.5):
// XLA folds x/0.05 -> x * 20.0f (fl32(1/0.05) == 20.0f exactly);
// __fmul_rn/__fadd_rn forbid FMA contraction. [R3: absmax 0.0 with this.]
__device__ __forceinline__ int bin_coord(float x) {
    float m = __fmul_rn(x, 20.0f);
    float r = __fadd_rn(m, 0.5f);
    return (int)floorf(r);
}

__global__ void zero_kernel(uint4* __restrict__ p, int n4) {
    int i = blockIdx.x * blockDim.x + threadIdx.x;
    if (i < n4) p[i] = make_uint4(0u, 0u, 0u, 0u);
}

// Phase 1: per-point voxel id + rank within voxel (one returning atomic per
// in-bounds point). Rank order is nondeterministic but max is commutative.
__global__ void hist_kernel(const float* __restrict__ coords,
                            int* __restrict__ counts,
                            int* __restrict__ vox,
                            int* __restrict__ rank,
                            int N) {
    int n = blockIdx.x * blockDim.x + threadIdx.x;
    int b = blockIdx.y;
    if (n >= N) return;
    const float* pc = coords + (size_t)b * 3 * N;
    int ix = bin_coord(pc[n]);
    int iy = bin_coord(pc[n + N]);
    int iz = bin_coord(pc[n + 2 * N]);
    bool ok = (unsigned)ix < (unsigned)GW && (unsigned)iy < (unsigned)GL &&
              (unsigned)iz < (unsigned)GH;
    int v = ok ? ((ix << 12) | (iy << 6) | iz) : -1;
    vox[(size_t)b * N + n] = v;
    if (ok) rank[(size_t)b * N + n] = atomicAdd(&counts[b * GV + v], 1);
}

// Phase 2a: per-block (1024 elements) exclusive scan + block sums.
__global__ void scan_blocks_kernel(const int* __restrict__ counts,
                                   int* __restrict__ offsets,
                                   int* __restrict__ blocksums) {
    __shared__ int lds[256];
    int t = threadIdx.x;
    int base = blockIdx.x * 1024 + t * 4;
    int4 c = *(const int4*)&counts[base];
    int s0 = c.x, s1 = s0 + c.y, s2 = s1 + c.z, s3 = s2 + c.w;
    lds[t] = s3;
    __syncthreads();
    for (int d = 1; d < 256; d <<= 1) {
        int v = (t >= d) ? lds[t - d] : 0;
        __syncthreads();
        if (t >= d) lds[t] += v;
        __syncthreads();
    }
    int excl = (t > 0) ? lds[t - 1] : 0;
    int4 o;
    o.x = excl; o.y = excl + s0; o.z = excl + s1; o.w = excl + s2;
    *(int4*)&offsets[base] = o;
    if (t == 255) blocksums[blockIdx.x] = lds[255];
}

// Phase 2b: exclusive scan of the 1024 block sums (single block), in place.
__global__ void scan_sums_kernel(int* __restrict__ blocksums) {
    __shared__ int lds[256];
    int t = threadIdx.x;
    int4 c = *(const int4*)&blocksums[t * 4];
    int s0 = c.x, s1 = s0 + c.y, s2 = s1 + c.z, s3 = s2 + c.w;
    lds[t] = s3;
    __syncthreads();
    for (int d = 1; d < 256; d <<= 1) {
        int v = (t >= d) ? lds[t - d] : 0;
        __syncthreads();
        if (t >= d) lds[t] += v;
        __syncthreads();
    }
    int excl = (t > 0) ? lds[t - 1] : 0;
    int4 o;
    o.x = excl; o.y = excl + s0; o.z = excl + s1; o.w = excl + s2;
    *(int4*)&blocksums[t * 4] = o;
}

// Phase 2c: add block offsets.
__global__ void scan_add_kernel(int* __restrict__ offsets,
                                const int* __restrict__ blocksums) {
    int i = blockIdx.x * blockDim.x + threadIdx.x;   // uint4 index
    int s = blocksums[(i * 4) >> 10];
    int4 o = *(int4*)&offsets[i * 4];
    o.x += s; o.y += s; o.z += s; o.w += s;
    *(int4*)&offsets[i * 4] = o;
}

// Phase 3: scatter point index into voxel-sorted position.
__global__ void scatter_idx_kernel(const int* __restrict__ vox,
                                   const int* __restrict__ rank,
                                   const int* __restrict__ offsets,
                                   int* __restrict__ sorted_idx,
                                   int N) {
    int n = blockIdx.x * blockDim.x + threadIdx.x;
    int b = blockIdx.y;
    if (n >= N) return;
    int v = vox[(size_t)b * N + n];
    if (v < 0) return;
    sorted_idx[offsets[b * GV + v] + rank[(size_t)b * N + n]] = n;
}

// Phase 4: segmented max. Thread = (b, c, v); consecutive lanes =
// consecutive voxels -> counts/offsets/vdata fully coalesced; sorted_idx
// reads near-coalesced (offsets monotone in v); attr gathers hit an
// L2-resident 800KB row. No atomics.
__global__ void segmax_kernel(const float* __restrict__ attrs,
                              const int* __restrict__ counts,
                              const int* __restrict__ offsets,
                              const int* __restrict__ sorted_idx,
                              float* __restrict__ vdata,
                              float* __restrict__ occ,
                              int N) {
    int t = blockIdx.x * blockDim.x + threadIdx.x;   // < NB*32*GV = 2^25
    int v = t & (GV - 1);
    int c = (t >> 18) & 31;
    int b = t >> 23;
    int bv = (b << 18) | v;
    int cnt = counts[bv];
    int off = offsets[bv];
    const float* row = attrs + ((size_t)(b * 32 + c)) * N;
    float m = -INFINITY;
    for (int k = 0; k < cnt; ++k) {
        m = fmaxf(m, row[sorted_idx[off + k]]);
    }
    vdata[((size_t)(b * 32 + c) << 18) | v] = (cnt > 0) ? m : 0.0f;
    if (c == 0) occ[bv] = (cnt >= MIN_PTS) ? 1.0f : 0.0f;
}

// ---------------------------------------------------------------------------
// FALLBACK PATH (R3): direct atomicMax into d_out, any C. (absmax 0, 1206us)
__device__ __forceinline__ unsigned enc_f32(float f) {
    unsigned u = __float_as_uint(f);
    return (u & 0x80000000u) ? ~u : (u | 0x80000000u);
}
__device__ __forceinline__ float dec_f32(unsigned u) {
    return (u & 0x80000000u) ? __uint_as_float(u & 0x7FFFFFFFu)
                             : __uint_as_float(~u);
}

__global__ void init_kernel(uint4* __restrict__ data4, uint4* __restrict__ cnt4,
                            int nData4, int nCnt4) {
    int i = blockIdx.x * blockDim.x + threadIdx.x;
    uint4 z = make_uint4(0u, 0u, 0u, 0u);
    if (i < nData4) data4[i] = z;
    else if (i < nData4 + nCnt4) cnt4[i - nData4] = z;
}

__global__ void scatter_kernel(const float* __restrict__ coords,
                               const float* __restrict__ attrs,
                               unsigned* __restrict__ bits,
                               int* __restrict__ counts,
                               int N, int C) {
    int n = blockIdx.x * blockDim.x + threadIdx.x;
    int b = blockIdx.y;
    if (n >= N) return;
    const float* pc = coords + (size_t)b * 3 * N;
    int ix = bin_coord(pc[n]);
    int iy = bin_coord(pc[n + N]);
    int iz = bin_coord(pc[n + 2 * N]);
    if ((unsigned)ix >= (unsigned)GW || (unsigned)iy >= (unsigned)GL ||
        (unsigned)iz >= (unsigned)GH)
        return;
    int v = (ix << 12) | (iy << 6) | iz;
    atomicAdd(&counts[b * GV + v], 1);
    const float* pa = attrs + (size_t)b * C * N + n;
    unsigned* pb = bits + (size_t)b * C * GV + v;
    for (int c = 0; c < C; ++c)
        atomicMax(&pb[(size_t)c * GV], enc_f32(pa[(size_t)c * N]));
}

__global__ void finalize_kernel(unsigned* __restrict__ data,
                                const int* __restrict__ counts,
                                float* __restrict__ occ, int C) {
    int i = blockIdx.x * blockDim.x + threadIdx.x;
    int nData4 = NB * C * GV / 4;
    int nOcc4 = NB * GV / 4;
    if (i < nData4) {
        int idx = i << 2;
        int v = idx & (GV - 1);
        int b = idx / (C * GV);
        int4 cv = *(const int4*)&counts[b * GV + v];
        uint4 u = *(const uint4*)&data[idx];
        float4 r;
        r.x = cv.x > 0 ? dec_f32(u.x) : 0.0f;
        r.y = cv.y > 0 ? dec_f32(u.y) : 0.0f;
        r.z = cv.z > 0 ? dec_f32(u.z) : 0.0f;
        r.w = cv.w > 0 ? dec_f32(u.w) : 0.0f;
        *(float4*)&data[idx] = r;
    } else if (i < nData4 + nOcc4) {
        int j = (i - nData4) << 2;
        int4 cv = *(const int4*)&counts[j];
        float4 r;
        r.x = cv.x >= MIN_PTS ? 1.0f : 0.0f;
        r.y = cv.y >= MIN_PTS ? 1.0f : 0.0f;
        r.z = cv.z >= MIN_PTS ? 1.0f : 0.0f;
        r.w = cv.w >= MIN_PTS ? 1.0f : 0.0f;
        *(float4*)&occ[j] = r;
    }
}

// ---------------------------------------------------------------------------
extern "C" void kernel_launch(void* const* d_in, const int* in_sizes, int n_in,
                              void* d_out, int out_size, void* d_ws, size_t ws_size,
                              hipStream_t stream) {
    const float* coords = (const float*)d_in[0];  // [B,3,N]
    const float* attrs  = (const float*)d_in[1];  // [B,C,N]
    int N = in_sizes[0] / (NB * 3);
    int C = in_sizes[1] / (NB * N);

    // ws layout (fast path): counts[B*GV] | offsets[B*GV] | blocksums[4096]
    //                        | vox[B*N] | rank[B*N] | sorted_idx[B*N]
    size_t needWs = (size_t)(2 * NB * GV + 4096 + 3 * NB * N) * 4;

    if (C == 32 && ws_size >= needWs) {
        int* counts     = (int*)d_ws;
        int* offsets    = counts + (size_t)NB * GV;
        int* blocksums  = offsets + (size_t)NB * GV;
        int* vox        = blocksums + 4096;
        int* rank       = vox + (size_t)NB * N;
        int* sorted_idx = rank + (size_t)NB * N;
        float* vdata    = (float*)d_out;                       // [B,32,V]
        float* occ      = (float*)d_out + (size_t)NB * 32 * GV;

        int nCnt4 = NB * GV / 4;                               // 262144
        zero_kernel<<<(nCnt4 + 255) / 256, 256, 0, stream>>>((uint4*)counts,
                                                             nCnt4);

        dim3 pgrid((N + 255) / 256, NB);
        hist_kernel<<<pgrid, 256, 0, stream>>>(coords, counts, vox, rank, N);

        scan_blocks_kernel<<<NB * GV / 1024, 256, 0, stream>>>(counts, offsets,
                                                               blocksums);
        scan_sums_kernel<<<1, 256, 0, stream>>>(blocksums);
        scan_add_kernel<<<NB * GV / 1024, 256, 0, stream>>>(offsets, blocksums);

        scatter_idx_kernel<<<pgrid, 256, 0, stream>>>(vox, rank, offsets,
                                                      sorted_idx, N);

        int segThreads = NB * 32 * GV;                         // 2^25
        segmax_kernel<<<segThreads / 256, 256, 0, stream>>>(
            attrs, counts, offsets, sorted_idx, vdata, occ, N);
    } else {
        unsigned* bits = (unsigned*)d_out;
        float* occ = (float*)d_out + (size_t)NB * C * GV;
        int* counts = (int*)d_ws;
        int nData4 = NB * C * GV / 4;
        int nCnt4 = NB * GV / 4;
        int initTotal = nData4 + nCnt4;
        init_kernel<<<(initTotal + 255) / 256, 256, 0, stream>>>(
            (uint4*)d_out, (uint4*)d_ws, nData4, nCnt4);
        dim3 sgrid((N + 255) / 256, NB);
        scatter_kernel<<<sgrid, 256, 0, stream>>>(coords, attrs, bits, counts,
                                                  N, C);
        finalize_kernel<<<(initTotal + 255) / 256, 256, 0, stream>>>(
            bits, counts, occ, C);
    }
}